// Round 2
// baseline (2683.627 us; speedup 1.0000x reference)
//
#include <hip/hip_runtime.h>
#include <math.h>

#define NNODES 81920
#define NEDGES 163840
#define NB     4096
#define HD     128

#define BM 128
#define BN 128
#define BKK 8

// ---------------- generic tiled fp32 GEMM ----------------
// mode 0: B row-major (K x N), ldb = row length
// mode 1: B stored (N x K) row-major (i.e. use B^T), ldb = K
// mode 2: B = We2 permuted view: B[k][n] = We2[(n>>7)*16384 + k*128 + (n&127)] (K=128, N=4096)
__global__ __launch_bounds__(256) void gemm_kernel(
    const float* __restrict__ A, const float* __restrict__ Bm,
    const float* __restrict__ bias, const float* __restrict__ addend,
    float* __restrict__ C,
    int M, int N, int K, int lda, int ldb, int ldc, int mode, int relu)
{
    __shared__ float As[BKK][BM + 4];
    __shared__ float Bs[BKK][BN + 4];
    const int tid = threadIdx.x;
    const int tx = tid & 15, ty = tid >> 4;
    const int m0 = blockIdx.y * BM, n0 = blockIdx.x * BN;
    float acc[8][8];
#pragma unroll
    for (int i = 0; i < 8; ++i)
#pragma unroll
        for (int j = 0; j < 8; ++j) acc[i][j] = 0.f;

    for (int k0 = 0; k0 < K; k0 += BKK) {
#pragma unroll
        for (int i = 0; i < 4; ++i) {
            int e = tid + i * 256;
            int r = e >> 3, kk = e & 7;
            int gm = m0 + r, gk = k0 + kk;
            As[kk][r] = (gm < M && gk < K) ? A[(size_t)gm * lda + gk] : 0.f;
        }
#pragma unroll
        for (int i = 0; i < 4; ++i) {
            int e = tid + i * 256;
            int kk = e >> 7, c = e & 127;
            int gk = k0 + kk, gn = n0 + c;
            float val = 0.f;
            if (gk < K && gn < N) {
                if (mode == 0)      val = Bm[(size_t)gk * ldb + gn];
                else if (mode == 1) val = Bm[(size_t)gn * ldb + gk];
                else                val = Bm[(size_t)(gn >> 7) * 16384 + gk * 128 + (gn & 127)];
            }
            Bs[kk][c] = val;
        }
        __syncthreads();
#pragma unroll
        for (int kk = 0; kk < BKK; ++kk) {
            float a[8], b[8];
#pragma unroll
            for (int i = 0; i < 8; ++i) a[i] = As[kk][ty * 8 + i];
#pragma unroll
            for (int j = 0; j < 8; ++j) b[j] = Bs[kk][tx * 8 + j];
#pragma unroll
            for (int i = 0; i < 8; ++i)
#pragma unroll
                for (int j = 0; j < 8; ++j)
                    acc[i][j] = fmaf(a[i], b[j], acc[i][j]);
        }
        __syncthreads();
    }
#pragma unroll
    for (int i = 0; i < 8; ++i) {
        int gm = m0 + ty * 8 + i;
        if (gm >= M) continue;
#pragma unroll
        for (int j = 0; j < 8; ++j) {
            int gn = n0 + tx * 8 + j;
            if (gn >= N) continue;
            float val = acc[i][j];
            if (bias)   val += bias[gn];
            if (addend) val += addend[(size_t)gm * ldc + gn];
            if (relu)   val = fmaxf(val, 0.f);
            C[(size_t)gm * ldc + gn] = val;
        }
    }
}

// ---------------- elementwise / graph kernels ----------------
__global__ void fill_kernel(float* __restrict__ p, float v, int n) {
    int i = blockIdx.x * blockDim.x + threadIdx.x;
    if (i < n) p[i] = v;
}

__global__ void count_deg_kernel(const int* __restrict__ dst, float* __restrict__ deg, int E) {
    int i = blockIdx.x * blockDim.x + threadIdx.x;
    if (i < E) atomicAdd(&deg[dst[i]], 1.0f);
}

__global__ void rsqrt_kernel(float* __restrict__ p, int n) {
    int i = blockIdx.x * blockDim.x + threadIdx.x;
    if (i < n) p[i] = rsqrtf(p[i]);
}

// out[n] = h[n] * dinv[n]^2  (the self-loop term; also serves as the zero-init of the aggregation buffer)
__global__ void init_self_kernel(const float* __restrict__ h, const float* __restrict__ dinv,
                                 float* __restrict__ out) {
    int i = blockIdx.x * blockDim.x + threadIdx.x;   // over NNODES*32 (float4 granules)
    if (i >= NNODES * 32) return;
    int n = i >> 5;
    float w = dinv[n]; w *= w;
    float4 v = reinterpret_cast<const float4*>(h)[i];
    v.x *= w; v.y *= w; v.z *= w; v.w *= w;
    reinterpret_cast<float4*>(out)[i] = v;
}

// out[dst] += h[src] * dinv[src]*dinv[dst], 32 threads (x float4) per edge
__global__ void scatter_kernel(const float* __restrict__ h, const int* __restrict__ src,
                               const int* __restrict__ dst, const float* __restrict__ dinv,
                               float* __restrict__ out, int E) {
    int t = blockIdx.x * blockDim.x + threadIdx.x;
    int e = t >> 5;
    if (e >= E) return;
    int c = t & 31;
    int s = src[e], d = dst[e];
    float w = dinv[s] * dinv[d];
    float4 v = reinterpret_cast<const float4*>(h + (size_t)s * HD)[c];
    float* o = out + (size_t)d * HD + c * 4;
    atomicAdd(o + 0, v.x * w);
    atomicAdd(o + 1, v.y * w);
    atomicAdd(o + 2, v.z * w);
    atomicAdd(o + 3, v.w * w);
}

__global__ void bias_relu_kernel(float* __restrict__ x, const float* __restrict__ b) {
    int i = blockIdx.x * blockDim.x + threadIdx.x;   // over NNODES*32
    if (i >= NNODES * 32) return;
    int c = i & 31;
    float4 v  = reinterpret_cast<float4*>(x)[i];
    float4 bb = reinterpret_cast<const float4*>(b)[c];
    v.x = fmaxf(v.x + bb.x, 0.f);
    v.y = fmaxf(v.y + bb.y, 0.f);
    v.z = fmaxf(v.z + bb.z, 0.f);
    v.w = fmaxf(v.w + bb.w, 0.f);
    reinterpret_cast<float4*>(x)[i] = v;
}

// mean over the 20 contiguous nodes of each graph
__global__ void pool_kernel(const float* __restrict__ x, float* __restrict__ xg) {
    int i = blockIdx.x * blockDim.x + threadIdx.x;   // NB*HD
    if (i >= NB * HD) return;
    int b = i >> 7, c = i & 127;
    const float* p = x + (size_t)b * 20 * HD + c;
    float s = 0.f;
#pragma unroll
    for (int r = 0; r < 20; ++r) s += p[r * HD];
    xg[i] = s * 0.05f;
}

__global__ void node_feat_kernel(const float* __restrict__ xg, const float* __restrict__ ap,
                                 const float* __restrict__ bp, const float* __restrict__ svt,
                                 const float* __restrict__ sut, float* __restrict__ nodef) {
    int i = blockIdx.x * blockDim.x + threadIdx.x;   // 2*NB*131
    if (i >= 2 * NB * 131) return;
    int row = i / 131, col = i - row * 131;
    float v;
    if (col < 128) v = xg[(size_t)row * 128 + col];
    else {
        int g = (row < NB) ? row : row - NB;
        if (col == 128)      v = ap[g];
        else if (col == 129) v = bp[g];
        else                 v = (row < NB) ? svt[g] : sut[g];
    }
    nodef[i] = v;
}

__global__ void edge_t_kernel(const float* __restrict__ svhb, const float* __restrict__ suhb,
                              const float* __restrict__ We1, const float* __restrict__ be1,
                              float* __restrict__ tsv, float* __restrict__ tsu) {
    int i = blockIdx.x * blockDim.x + threadIdx.x;   // NB*32
    if (i >= NB * 32) return;
    int g = i >> 5, k = i & 31;
    tsv[i] = fmaxf(svhb[g] * We1[k] + be1[k], 0.f);
    tsu[i] = fmaxf(suhb[g] * We1[k] + be1[k], 0.f);
}

// aggr[i]    = sum_k tsv[k]*(C[i][k,:] + C[B+i][k,:]) + v[i] + v[B+i]
// aggr[B+i]  = sum_k (tsv[k]*C[i][k,:] + tsu[k]*C[B+i][k,:]) + v[i] + v[B+i]
__global__ void assembly_kernel(const float* __restrict__ C, const float* __restrict__ v,
                                const float* __restrict__ tsv, const float* __restrict__ tsu,
                                float* __restrict__ aggr) {
    int i = blockIdx.x;      // graph
    int o = threadIdx.x;     // 0..127
    __shared__ float sv[32], su[32];
    if (o < 32)       sv[o] = tsv[(size_t)i * 32 + o];
    else if (o < 64)  su[o - 32] = tsu[(size_t)i * 32 + (o - 32)];
    __syncthreads();
    const float* Ci = C + (size_t)i * 4096;
    const float* Cs = C + (size_t)(NB + i) * 4096;
    float ai = 0.f, as = 0.f;
#pragma unroll
    for (int k = 0; k < 32; ++k) {
        float ci = Ci[k * 128 + o], cs = Cs[k * 128 + o];
        ai += sv[k] * (ci + cs);
        as += sv[k] * ci + su[k] * cs;
    }
    float vv = v[(size_t)i * 128 + o] + v[(size_t)(NB + i) * 128 + o];
    aggr[(size_t)i * 128 + o]        = ai + vv;
    aggr[(size_t)(NB + i) * 128 + o] = as + vv;
}

__global__ void gru_kernel(const float* __restrict__ gi, const float* __restrict__ gh,
                           const float* __restrict__ h0, float* __restrict__ hout) {
    int i = blockIdx.x * blockDim.x + threadIdx.x;   // 2*NB*128
    if (i >= 2 * NB * HD) return;
    int n = i >> 7, c = i & 127;
    const float* gin = gi + (size_t)n * 384;
    const float* ghn = gh + (size_t)n * 384;
    float r = gin[c] + ghn[c];
    float z = gin[128 + c] + ghn[128 + c];
    r = 1.f / (1.f + expf(-r));
    z = 1.f / (1.f + expf(-z));
    float nn = tanhf(gin[256 + c] + r * ghn[256 + c]);
    hout[i] = (1.f - z) * nn + z * h0[i];
}

__global__ void xgm_kernel(const float* __restrict__ h, const float* __restrict__ Tx,
                           float* __restrict__ xgm) {
    int i = blockIdx.x * blockDim.x + threadIdx.x;   // NB*257
    if (i >= NB * 257) return;
    int row = i / 257, col = i - row * 257;
    float v;
    if (col < 128)      v = h[(size_t)row * 128 + col];
    else if (col < 256) v = h[(size_t)(NB + row) * 128 + (col - 128)];
    else                v = (Tx[row] + 60.f) * (1.f / 349.3f);
    xgm[i] = v;
}

// ---------------- launcher ----------------
extern "C" void kernel_launch(void* const* d_in, const int* in_sizes, int n_in,
                              void* d_out, int out_size, void* d_ws, size_t ws_size,
                              hipStream_t stream)
{
    const float* sv_x   = (const float*)d_in[0];
    const int*   sv_ei  = (const int*)d_in[1];
    const float* su_x   = (const float*)d_in[3];
    const int*   su_ei  = (const int*)d_in[4];
    const float* ap     = (const float*)d_in[6];
    const float* bp     = (const float*)d_in[7];
    const float* sv_top = (const float*)d_in[8];
    const float* su_top = (const float*)d_in[9];
    const float* sv_hb  = (const float*)d_in[10];
    const float* su_hb  = (const float*)d_in[11];
    const float* T_x    = (const float*)d_in[12];
    const float* W_gcn1 = (const float*)d_in[13];
    const float* b_gcn1 = (const float*)d_in[14];
    const float* W_gcn2 = (const float*)d_in[15];
    const float* b_gcn2 = (const float*)d_in[16];
    const float* Wp     = (const float*)d_in[17];
    const float* bp_pr  = (const float*)d_in[18];
    const float* We1    = (const float*)d_in[19];
    const float* be1    = (const float*)d_in[20];
    const float* We2    = (const float*)d_in[21];
    const float* be2    = (const float*)d_in[22];
    const float* W_root = (const float*)d_in[23];
    const float* b_nn   = (const float*)d_in[24];
    const float* W_ih   = (const float*)d_in[25];
    const float* W_hh   = (const float*)d_in[26];
    const float* b_ih   = (const float*)d_in[27];
    const float* b_hh   = (const float*)d_in[28];
    const float* Wm1    = (const float*)d_in[29];
    const float* bm1    = (const float*)d_in[30];
    const float* Wm2    = (const float*)d_in[31];
    const float* bm2    = (const float*)d_in[32];
    const float* Wm3    = (const float*)d_in[33];
    const float* bm3    = (const float*)d_in[34];
    float* out = (float*)d_out;

    float* ws = (float*)d_ws;
    const size_t BIGF = (size_t)2 * NB * 4096;      // 33,554,432 floats (C buffer)
    // big region: GCN staging (h_tmp + h_agg) then C, then GRU/MLP temporaries
    float* Cbuf  = ws;
    float* h_tmp = ws;
    float* h_agg = ws + (size_t)NNODES * HD;
    float* gi    = ws;                  // valid after Cbuf is dead
    float* gh    = ws + 3145728;
    float* xgm   = ws + 6291456;
    float* o1    = ws + 7344128;
    float* o2    = ws + 8392704;
    // persistent small region
    float* p = ws + BIGF;
    float* deg   = p; p += NNODES;                  // becomes dinv in-place
    float* xg    = p; p += (size_t)2 * NB * HD;
    float* nodef = p; p += (size_t)2 * NB * 131;
    float* h0    = p; p += (size_t)2 * NB * HD;
    float* tsv   = p; p += (size_t)NB * 32;
    float* tsu   = p; p += (size_t)NB * 32;
    float* vbuf  = p; p += (size_t)2 * NB * HD;
    float* aggrb = p; p += (size_t)2 * NB * HD;
    float* nf    = p; p += (size_t)2 * NB * HD;
    float* hout  = p; p += (size_t)2 * NB * HD;
    size_t need_bytes = (size_t)(p - ws) * sizeof(float);
    if (ws_size < need_bytes) {
        // diagnosable failure: sentinel output
        fill_kernel<<<(out_size + 255) / 256, 256, 0, stream>>>(out, -1.0e6f, out_size);
        return;
    }

    auto gemm = [&](const float* A, const float* Bmat, const float* bias, const float* add,
                    float* Cc, int M, int Nn, int K, int lda, int ldb, int ldc, int mode, int relu) {
        dim3 g((Nn + BN - 1) / BN, (M + BM - 1) / BM);
        gemm_kernel<<<g, 256, 0, stream>>>(A, Bmat, bias, add, Cc, M, Nn, K, lda, ldb, ldc, mode, relu);
    };

    auto run_gcn = [&](const float* x, const int* ei, float* xg_out) {
        const int* src = ei;
        const int* dst = ei + NEDGES;
        fill_kernel<<<(NNODES + 255) / 256, 256, 0, stream>>>(deg, 1.0f, NNODES);
        count_deg_kernel<<<(NEDGES + 255) / 256, 256, 0, stream>>>(dst, deg, NEDGES);
        rsqrt_kernel<<<(NNODES + 255) / 256, 256, 0, stream>>>(deg, NNODES);
        // conv1: h_tmp = x @ W_gcn1
        gemm(x, W_gcn1, nullptr, nullptr, h_tmp, NNODES, HD, 74, 74, HD, HD, 0, 0);
        init_self_kernel<<<(NNODES * 32 + 255) / 256, 256, 0, stream>>>(h_tmp, deg, h_agg);
        scatter_kernel<<<(NEDGES * 32 + 255) / 256, 256, 0, stream>>>(h_tmp, src, dst, deg, h_agg, NEDGES);
        bias_relu_kernel<<<(NNODES * 32 + 255) / 256, 256, 0, stream>>>(h_agg, b_gcn1);
        // conv2: h_tmp = x1 @ W_gcn2
        gemm(h_agg, W_gcn2, nullptr, nullptr, h_tmp, NNODES, HD, HD, HD, HD, HD, 0, 0);
        init_self_kernel<<<(NNODES * 32 + 255) / 256, 256, 0, stream>>>(h_tmp, deg, h_agg);
        scatter_kernel<<<(NEDGES * 32 + 255) / 256, 256, 0, stream>>>(h_tmp, src, dst, deg, h_agg, NEDGES);
        bias_relu_kernel<<<(NNODES * 32 + 255) / 256, 256, 0, stream>>>(h_agg, b_gcn2);
        pool_kernel<<<(NB * HD + 255) / 256, 256, 0, stream>>>(h_agg, xg_out);
    };

    run_gcn(sv_x, sv_ei, xg);
    run_gcn(su_x, su_ei, xg + (size_t)NB * HD);

    // MPNN
    node_feat_kernel<<<(2 * NB * 131 + 255) / 256, 256, 0, stream>>>(xg, ap, bp, sv_top, su_top, nodef);
    gemm(nodef, Wp, bp_pr, nullptr, h0, 2 * NB, HD, 131, 131, HD, HD, 0, 1);
    edge_t_kernel<<<(NB * 32 + 255) / 256, 256, 0, stream>>>(sv_hb, su_hb, We1, be1, tsv, tsu);
    // C = h0 @ W~  (W~[h][k*128+o] = We2[k][h*128+o]), and v = h0 @ reshape(be2,H,H)
    gemm(h0, We2, nullptr, nullptr, Cbuf, 2 * NB, 4096, HD, HD, 0, 4096, 2, 0);
    gemm(h0, be2, nullptr, nullptr, vbuf, 2 * NB, HD, HD, HD, HD, HD, 0, 0);
    assembly_kernel<<<NB, 128, 0, stream>>>(Cbuf, vbuf, tsv, tsu, aggrb);
    // nf = relu(h0 @ W_root + aggr + b_nn)
    gemm(h0, W_root, b_nn, aggrb, nf, 2 * NB, HD, HD, HD, HD, HD, 0, 1);
    // GRU gates
    gemm(nf, W_ih, b_ih, nullptr, gi, 2 * NB, 384, HD, HD, HD, 384, 1, 0);
    gemm(h0, W_hh, b_hh, nullptr, gh, 2 * NB, 384, HD, HD, HD, 384, 1, 0);
    gru_kernel<<<(2 * NB * HD + 255) / 256, 256, 0, stream>>>(gi, gh, h0, hout);
    // output MLP
    xgm_kernel<<<(NB * 257 + 255) / 256, 256, 0, stream>>>(hout, T_x, xgm);
    gemm(xgm, Wm1, bm1, nullptr, o1, NB, 256, 257, 257, 256, 256, 0, 1);
    gemm(o1, Wm2, bm2, nullptr, o2, NB, HD, 256, 256, HD, HD, 0, 1);
    gemm(o2, Wm3, bm3, nullptr, out, NB, 1, HD, HD, 1, 1, 0, 0);
}

// Round 4
// 1646.567 us; speedup vs baseline: 1.6298x; 1.6298x over previous
//
#include <hip/hip_runtime.h>
#include <math.h>

#define NNODES 81920
#define NEDGES 163840
#define NB     4096
#define HD     128

#define BM 128
#define BN 128
#define BKK 8

// ---------------- generic tiled fp32 GEMM ----------------
// mode 0: B row-major (K x N), ldb = row length
// mode 1: B stored (N x K) row-major (i.e. use B^T), ldb = K
// mode 2: B = We2 permuted view: B[k][n] = We2[(n>>7)*16384 + k*128 + (n&127)] (K=128, N=4096)
__global__ __launch_bounds__(256) void gemm_kernel(
    const float* __restrict__ A, const float* __restrict__ Bm,
    const float* __restrict__ bias, const float* __restrict__ addend,
    float* __restrict__ C,
    int M, int N, int K, int lda, int ldb, int ldc, int mode, int relu)
{
    __shared__ float As[BKK][BM + 4];
    __shared__ float Bs[BKK][BN + 4];
    const int tid = threadIdx.x;
    const int tx = tid & 15, ty = tid >> 4;
    const int m0 = blockIdx.y * BM, n0 = blockIdx.x * BN;
    float acc[8][8];
#pragma unroll
    for (int i = 0; i < 8; ++i)
#pragma unroll
        for (int j = 0; j < 8; ++j) acc[i][j] = 0.f;

    for (int k0 = 0; k0 < K; k0 += BKK) {
#pragma unroll
        for (int i = 0; i < 4; ++i) {
            int e = tid + i * 256;
            int r = e >> 3, kk = e & 7;
            int gm = m0 + r, gk = k0 + kk;
            As[kk][r] = (gm < M && gk < K) ? A[(size_t)gm * lda + gk] : 0.f;
        }
#pragma unroll
        for (int i = 0; i < 4; ++i) {
            int e = tid + i * 256;
            int kk = e >> 7, c = e & 127;
            int gk = k0 + kk, gn = n0 + c;
            float val = 0.f;
            if (gk < K && gn < N) {
                if (mode == 0)      val = Bm[(size_t)gk * ldb + gn];
                else if (mode == 1) val = Bm[(size_t)gn * ldb + gk];
                else                val = Bm[(size_t)(gn >> 7) * 16384 + gk * 128 + (gn & 127)];
            }
            Bs[kk][c] = val;
        }
        __syncthreads();
#pragma unroll
        for (int kk = 0; kk < BKK; ++kk) {
            float a[8], b[8];
#pragma unroll
            for (int i = 0; i < 8; ++i) a[i] = As[kk][ty * 8 + i];
#pragma unroll
            for (int j = 0; j < 8; ++j) b[j] = Bs[kk][tx * 8 + j];
#pragma unroll
            for (int i = 0; i < 8; ++i)
#pragma unroll
                for (int j = 0; j < 8; ++j)
                    acc[i][j] = fmaf(a[i], b[j], acc[i][j]);
        }
        __syncthreads();
    }
#pragma unroll
    for (int i = 0; i < 8; ++i) {
        int gm = m0 + ty * 8 + i;
        if (gm >= M) continue;
#pragma unroll
        for (int j = 0; j < 8; ++j) {
            int gn = n0 + tx * 8 + j;
            if (gn >= N) continue;
            float val = acc[i][j];
            if (bias)   val += bias[gn];
            if (addend) val += addend[(size_t)gm * ldc + gn];
            if (relu)   val = fmaxf(val, 0.f);
            C[(size_t)gm * ldc + gn] = val;
        }
    }
}

// ---------------- elementwise / graph kernels ----------------
__global__ void fill_kernel(float* __restrict__ p, float v, int n) {
    int i = blockIdx.x * blockDim.x + threadIdx.x;
    if (i < n) p[i] = v;
}

__global__ void fill_int_kernel(int* __restrict__ p, int v, int n) {
    int i = blockIdx.x * blockDim.x + threadIdx.x;
    if (i < n) p[i] = v;
}

// ---- CSR build (per molecule, shared by conv1 & conv2) ----
__global__ void hist_kernel(const int* __restrict__ dst, int* __restrict__ deg, int E) {
    int i = blockIdx.x * blockDim.x + threadIdx.x;
    if (i < E) atomicAdd(&deg[dst[i]], 1);
}

__global__ void dinv_kernel(const int* __restrict__ deg, float* __restrict__ dinv, int n) {
    int i = blockIdx.x * blockDim.x + threadIdx.x;
    if (i < n) dinv[i] = rsqrtf((float)deg[i] + 1.0f);   // +1 for self loop
}

// exclusive scan of deg within 256-blocks; bsum[b] = block total
__global__ void scan_block_kernel(const int* __restrict__ deg, int* __restrict__ rp,
                                  int* __restrict__ bsum) {
    __shared__ int s[256];
    int t = threadIdx.x;
    int i = blockIdx.x * 256 + t;
    int v = deg[i];
    s[t] = v;
    __syncthreads();
    int x = v;
    for (int off = 1; off < 256; off <<= 1) {
        int y = (t >= off) ? s[t - off] : 0;
        __syncthreads();
        x += y; s[t] = x;
        __syncthreads();
    }
    rp[i] = x - v;
    if (t == 255) bsum[blockIdx.x] = x;
}

// exclusive scan of nb (<512) block sums, single block of 512
__global__ void scan_bsum_kernel(int* __restrict__ bsum, int nb) {
    __shared__ int s[512];
    int t = threadIdx.x;
    int v = (t < nb) ? bsum[t] : 0;
    s[t] = v;
    __syncthreads();
    int x = v;
    for (int off = 1; off < 512; off <<= 1) {
        int y = (t >= off) ? s[t - off] : 0;
        __syncthreads();
        x += y; s[t] = x;
        __syncthreads();
    }
    if (t < nb) bsum[t] = x - v;
}

__global__ void add_offsets_kernel(int* __restrict__ rp, const int* __restrict__ bsum,
                                   int* __restrict__ cursor) {
    int i = blockIdx.x * 256 + threadIdx.x;
    int v = rp[i] + bsum[blockIdx.x];
    rp[i] = v;
    cursor[i] = v;
}

__global__ void csr_fill_kernel(const int* __restrict__ src, const int* __restrict__ dst,
                                const float* __restrict__ dinv, int* __restrict__ cursor,
                                int* __restrict__ ssrc, float* __restrict__ sw, int E) {
    int e = blockIdx.x * blockDim.x + threadIdx.x;
    if (e >= E) return;
    int s = src[e], d = dst[e];
    int pos = atomicAdd(&cursor[d], 1);
    ssrc[pos] = s;
    sw[pos] = dinv[s] * dinv[d];
}

// ---- fused GCN aggregation: out[n] = relu( h[n]*dinv[n]^2 + sum_e h[src_e]*w_e + bias )
// thread = (node, float4 chunk); after csr_fill, cursor[n] = row end
__global__ void gather_kernel(const float* __restrict__ h, const int* __restrict__ rp,
                              const int* __restrict__ rend, const int* __restrict__ ssrc,
                              const float* __restrict__ sw, const float* __restrict__ dinv,
                              const float* __restrict__ bias, float* __restrict__ out) {
    int t = blockIdx.x * blockDim.x + threadIdx.x;
    if (t >= NNODES * 32) return;
    int n = t >> 5, c = t & 31;
    float w0 = dinv[n]; w0 *= w0;
    float4 acc = reinterpret_cast<const float4*>(h + (size_t)n * HD)[c];
    acc.x *= w0; acc.y *= w0; acc.z *= w0; acc.w *= w0;
    int beg = rp[n], end = rend[n];
    for (int e = beg; e < end; ++e) {
        int s = ssrc[e];
        float w = sw[e];
        float4 v = reinterpret_cast<const float4*>(h + (size_t)s * HD)[c];
        acc.x += v.x * w; acc.y += v.y * w; acc.z += v.z * w; acc.w += v.w * w;
    }
    float4 bb = reinterpret_cast<const float4*>(bias)[c];
    acc.x = fmaxf(acc.x + bb.x, 0.f);
    acc.y = fmaxf(acc.y + bb.y, 0.f);
    acc.z = fmaxf(acc.z + bb.z, 0.f);
    acc.w = fmaxf(acc.w + bb.w, 0.f);
    reinterpret_cast<float4*>(out)[t] = acc;
}

// mean over the 20 contiguous nodes of each graph
__global__ void pool_kernel(const float* __restrict__ x, float* __restrict__ xg) {
    int i = blockIdx.x * blockDim.x + threadIdx.x;   // NB*HD
    if (i >= NB * HD) return;
    int b = i >> 7, c = i & 127;
    const float* p = x + (size_t)b * 20 * HD + c;
    float s = 0.f;
#pragma unroll
    for (int r = 0; r < 20; ++r) s += p[r * HD];
    xg[i] = s * 0.05f;
}

__global__ void node_feat_kernel(const float* __restrict__ xg, const float* __restrict__ ap,
                                 const float* __restrict__ bp, const float* __restrict__ svt,
                                 const float* __restrict__ sut, float* __restrict__ nodef) {
    int i = blockIdx.x * blockDim.x + threadIdx.x;   // 2*NB*131
    if (i >= 2 * NB * 131) return;
    int row = i / 131, col = i - row * 131;
    float v;
    if (col < 128) v = xg[(size_t)row * 128 + col];
    else {
        int g = (row < NB) ? row : row - NB;
        if (col == 128)      v = ap[g];
        else if (col == 129) v = bp[g];
        else                 v = (row < NB) ? svt[g] : sut[g];
    }
    nodef[i] = v;
}

__global__ void edge_t_kernel(const float* __restrict__ svhb, const float* __restrict__ suhb,
                              const float* __restrict__ We1, const float* __restrict__ be1,
                              float* __restrict__ tsv, float* __restrict__ tsu) {
    int i = blockIdx.x * blockDim.x + threadIdx.x;   // NB*32
    if (i >= NB * 32) return;
    int g = i >> 5, k = i & 31;
    tsv[i] = fmaxf(svhb[g] * We1[k] + be1[k], 0.f);
    tsu[i] = fmaxf(suhb[g] * We1[k] + be1[k], 0.f);
}

// aggr[i]    = sum_k tsv[k]*(C[i][k,:] + C[B+i][k,:]) + v[i] + v[B+i]
// aggr[B+i]  = sum_k (tsv[k]*C[i][k,:] + tsu[k]*C[B+i][k,:]) + v[i] + v[B+i]
__global__ void assembly_kernel(const float* __restrict__ C, const float* __restrict__ v,
                                const float* __restrict__ tsv, const float* __restrict__ tsu,
                                float* __restrict__ aggr) {
    int i = blockIdx.x;      // graph
    int o = threadIdx.x;     // 0..127
    __shared__ float sv[32], su[32];
    if (o < 32)       sv[o] = tsv[(size_t)i * 32 + o];
    else if (o < 64)  su[o - 32] = tsu[(size_t)i * 32 + (o - 32)];
    __syncthreads();
    const float* Ci = C + (size_t)i * 4096;
    const float* Cs = C + (size_t)(NB + i) * 4096;
    float ai = 0.f, as = 0.f;
#pragma unroll
    for (int k = 0; k < 32; ++k) {
        float ci = Ci[k * 128 + o], cs = Cs[k * 128 + o];
        ai += sv[k] * (ci + cs);
        as += sv[k] * ci + su[k] * cs;
    }
    float vv = v[(size_t)i * 128 + o] + v[(size_t)(NB + i) * 128 + o];
    aggr[(size_t)i * 128 + o]        = ai + vv;
    aggr[(size_t)(NB + i) * 128 + o] = as + vv;
}

__global__ void gru_kernel(const float* __restrict__ gi, const float* __restrict__ gh,
                           const float* __restrict__ h0, float* __restrict__ hout) {
    int i = blockIdx.x * blockDim.x + threadIdx.x;   // 2*NB*128
    if (i >= 2 * NB * HD) return;
    int n = i >> 7, c = i & 127;
    const float* gin = gi + (size_t)n * 384;
    const float* ghn = gh + (size_t)n * 384;
    float r = gin[c] + ghn[c];
    float z = gin[128 + c] + ghn[128 + c];
    r = 1.f / (1.f + expf(-r));
    z = 1.f / (1.f + expf(-z));
    float nn = tanhf(gin[256 + c] + r * ghn[256 + c]);
    hout[i] = (1.f - z) * nn + z * h0[i];
}

__global__ void xgm_kernel(const float* __restrict__ h, const float* __restrict__ Tx,
                           float* __restrict__ xgm) {
    int i = blockIdx.x * blockDim.x + threadIdx.x;   // NB*257
    if (i >= NB * 257) return;
    int row = i / 257, col = i - row * 257;
    float v;
    if (col < 128)      v = h[(size_t)row * 128 + col];
    else if (col < 256) v = h[(size_t)(NB + row) * 128 + (col - 128)];
    else                v = (Tx[row] + 60.f) * (1.f / 349.3f);
    xgm[i] = v;
}

// ---------------- launcher ----------------
extern "C" void kernel_launch(void* const* d_in, const int* in_sizes, int n_in,
                              void* d_out, int out_size, void* d_ws, size_t ws_size,
                              hipStream_t stream)
{
    const float* sv_x   = (const float*)d_in[0];
    const int*   sv_ei  = (const int*)d_in[1];
    const float* su_x   = (const float*)d_in[3];
    const int*   su_ei  = (const int*)d_in[4];
    const float* ap     = (const float*)d_in[6];
    const float* bp     = (const float*)d_in[7];
    const float* sv_top = (const float*)d_in[8];
    const float* su_top = (const float*)d_in[9];
    const float* sv_hb  = (const float*)d_in[10];
    const float* su_hb  = (const float*)d_in[11];
    const float* T_x    = (const float*)d_in[12];
    const float* W_gcn1 = (const float*)d_in[13];
    const float* b_gcn1 = (const float*)d_in[14];
    const float* W_gcn2 = (const float*)d_in[15];
    const float* b_gcn2 = (const float*)d_in[16];
    const float* Wp     = (const float*)d_in[17];
    const float* bp_pr  = (const float*)d_in[18];
    const float* We1    = (const float*)d_in[19];
    const float* be1    = (const float*)d_in[20];
    const float* We2    = (const float*)d_in[21];
    const float* be2    = (const float*)d_in[22];
    const float* W_root = (const float*)d_in[23];
    const float* b_nn   = (const float*)d_in[24];
    const float* W_ih   = (const float*)d_in[25];
    const float* W_hh   = (const float*)d_in[26];
    const float* b_ih   = (const float*)d_in[27];
    const float* b_hh   = (const float*)d_in[28];
    const float* Wm1    = (const float*)d_in[29];
    const float* bm1    = (const float*)d_in[30];
    const float* Wm2    = (const float*)d_in[31];
    const float* bm2    = (const float*)d_in[32];
    const float* Wm3    = (const float*)d_in[33];
    const float* bm3    = (const float*)d_in[34];
    float* out = (float*)d_out;

    float* ws = (float*)d_ws;
    const size_t BIGF = (size_t)2 * NB * 4096;      // 33,554,432 floats (C buffer)
    // big region: GCN staging (h_tmp + h_agg) then C, then GRU/MLP temporaries
    float* Cbuf  = ws;
    float* h_tmp = ws;
    float* h_agg = ws + (size_t)NNODES * HD;
    float* gi    = ws;                  // valid after Cbuf is dead
    float* gh    = ws + 3145728;
    float* xgm   = ws + 6291456;
    float* o1    = ws + 7344128;
    float* o2    = ws + 8392704;
    // persistent small region
    float* p = ws + BIGF;
    float* xg    = p; p += (size_t)2 * NB * HD;
    float* nodef = p; p += (size_t)2 * NB * 131;
    float* h0    = p; p += (size_t)2 * NB * HD;
    float* tsv   = p; p += (size_t)NB * 32;
    float* tsu   = p; p += (size_t)NB * 32;
    float* vbuf  = p; p += (size_t)2 * NB * HD;
    float* aggrb = p; p += (size_t)2 * NB * HD;
    float* nf    = p; p += (size_t)2 * NB * HD;
    float* hout  = p; p += (size_t)2 * NB * HD;
    // CSR buffers (rebuilt per molecule, reused by conv1+conv2)
    float* dinv  = p; p += NNODES;
    int* deg_i   = (int*)p; p += NNODES;
    int* row_ptr = (int*)p; p += NNODES;
    int* cursor  = (int*)p; p += NNODES;
    int* bsum    = (int*)p; p += 512;
    int* ssrc    = (int*)p; p += NEDGES;
    float* sw    = p; p += NEDGES;
    size_t need_bytes = (size_t)(p - ws) * sizeof(float);
    if (ws_size < need_bytes) {
        // diagnosable failure: sentinel output
        fill_kernel<<<(out_size + 255) / 256, 256, 0, stream>>>(out, -1.0e6f, out_size);
        return;
    }

    auto gemm = [&](const float* A, const float* Bmat, const float* bias, const float* add,
                    float* Cc, int M, int Nn, int K, int lda, int ldb, int ldc, int mode, int relu) {
        dim3 g((Nn + BN - 1) / BN, (M + BM - 1) / BM);
        gemm_kernel<<<g, 256, 0, stream>>>(A, Bmat, bias, add, Cc, M, Nn, K, lda, ldb, ldc, mode, relu);
    };

    auto run_gcn = [&](const float* x, const int* ei, float* xg_out) {
        const int* src = ei;
        const int* dst = ei + NEDGES;
        // --- CSR build (once per molecule) ---
        fill_int_kernel<<<(NNODES + 255) / 256, 256, 0, stream>>>(deg_i, 0, NNODES);
        hist_kernel<<<(NEDGES + 255) / 256, 256, 0, stream>>>(dst, deg_i, NEDGES);
        dinv_kernel<<<(NNODES + 255) / 256, 256, 0, stream>>>(deg_i, dinv, NNODES);
        scan_block_kernel<<<NNODES / 256, 256, 0, stream>>>(deg_i, row_ptr, bsum);
        scan_bsum_kernel<<<1, 512, 0, stream>>>(bsum, NNODES / 256);
        add_offsets_kernel<<<NNODES / 256, 256, 0, stream>>>(row_ptr, bsum, cursor);
        csr_fill_kernel<<<(NEDGES + 255) / 256, 256, 0, stream>>>(src, dst, dinv, cursor, ssrc, sw, NEDGES);
        // --- conv1 ---
        gemm(x, W_gcn1, nullptr, nullptr, h_tmp, NNODES, HD, 74, 74, HD, HD, 0, 0);
        gather_kernel<<<(NNODES * 32 + 255) / 256, 256, 0, stream>>>(
            h_tmp, row_ptr, cursor, ssrc, sw, dinv, b_gcn1, h_agg);
        // --- conv2 ---
        gemm(h_agg, W_gcn2, nullptr, nullptr, h_tmp, NNODES, HD, HD, HD, HD, HD, 0, 0);
        gather_kernel<<<(NNODES * 32 + 255) / 256, 256, 0, stream>>>(
            h_tmp, row_ptr, cursor, ssrc, sw, dinv, b_gcn2, h_agg);
        pool_kernel<<<(NB * HD + 255) / 256, 256, 0, stream>>>(h_agg, xg_out);
    };

    run_gcn(sv_x, sv_ei, xg);
    run_gcn(su_x, su_ei, xg + (size_t)NB * HD);

    // MPNN
    node_feat_kernel<<<(2 * NB * 131 + 255) / 256, 256, 0, stream>>>(xg, ap, bp, sv_top, su_top, nodef);
    gemm(nodef, Wp, bp_pr, nullptr, h0, 2 * NB, HD, 131, 131, HD, HD, 0, 1);
    edge_t_kernel<<<(NB * 32 + 255) / 256, 256, 0, stream>>>(sv_hb, su_hb, We1, be1, tsv, tsu);
    // C = h0 @ W~  (W~[h][k*128+o] = We2[k][h*128+o]), and v = h0 @ reshape(be2,H,H)
    gemm(h0, We2, nullptr, nullptr, Cbuf, 2 * NB, 4096, HD, HD, 0, 4096, 2, 0);
    gemm(h0, be2, nullptr, nullptr, vbuf, 2 * NB, HD, HD, HD, HD, HD, 0, 0);
    assembly_kernel<<<NB, 128, 0, stream>>>(Cbuf, vbuf, tsv, tsu, aggrb);
    // nf = relu(h0 @ W_root + aggr + b_nn)
    gemm(h0, W_root, b_nn, aggrb, nf, 2 * NB, HD, HD, HD, HD, HD, 0, 1);
    // GRU gates
    gemm(nf, W_ih, b_ih, nullptr, gi, 2 * NB, 384, HD, HD, HD, 384, 1, 0);
    gemm(h0, W_hh, b_hh, nullptr, gh, 2 * NB, 384, HD, HD, HD, 384, 1, 0);
    gru_kernel<<<(2 * NB * HD + 255) / 256, 256, 0, stream>>>(gi, gh, h0, hout);
    // output MLP
    xgm_kernel<<<(NB * 257 + 255) / 256, 256, 0, stream>>>(hout, T_x, xgm);
    gemm(xgm, Wm1, bm1, nullptr, o1, NB, 256, 257, 257, 256, 256, 0, 1);
    gemm(o1, Wm2, bm2, nullptr, o2, NB, HD, 256, 256, HD, HD, 0, 1);
    gemm(o2, Wm3, bm3, nullptr, out, NB, 1, HD, HD, 1, 1, 0, 0);
}

// Round 6
// 1055.215 us; speedup vs baseline: 2.5432x; 1.5604x over previous
//
#include <hip/hip_runtime.h>
#include <math.h>

#define NNODES 81920
#define NEDGES 163840
#define NB     4096
#define HD     128

#define BM 128
#define BN 128
#define BKK 8

typedef __attribute__((ext_vector_type(8))) short bf16x8;
typedef __attribute__((ext_vector_type(4))) float f32x4;

#define LDK 40  // LDS k-stride in ushorts (80B rows: 20-bank stride, <=2-way conflicts)

// ---------------- split-bf16 MFMA GEMM ----------------
// C[M][N] = A[M][K] * B[K][N] (+bias), with A given as hi/lo bf16 planes (row-major,
// stride K) and B given as B^T hi/lo planes (N x K row-major). K multiple of 32,
// M,N multiples of 128 (N also allows 384 etc.). acc = Ah*Bh + Ah*Bl + Al*Bh.
__global__ __launch_bounds__(256) void mfma_gemm_kernel(
    const unsigned short* __restrict__ Ahi, const unsigned short* __restrict__ Alo,
    const unsigned short* __restrict__ Bthi, const unsigned short* __restrict__ Btlo,
    const float* __restrict__ bias, float* __restrict__ C,
    int M, int N, int K, int ldc)
{
    __shared__ unsigned short sAh[128 * LDK], sAl[128 * LDK];
    __shared__ unsigned short sBh[128 * LDK], sBl[128 * LDK];
    const int tid  = threadIdx.x;
    const int lane = tid & 63;
    const int wid  = tid >> 6;
    const int wm   = wid >> 1, wn = wid & 1;       // 2x2 waves of 64x64
    const int m0   = blockIdx.y * 128, n0 = blockIdx.x * 128;
    const int lrow = lane & 15;
    const int lk   = (lane >> 4) << 3;             // k offset 0/8/16/24

    f32x4 acc[4][4];
#pragma unroll
    for (int i = 0; i < 4; ++i)
#pragma unroll
        for (int j = 0; j < 4; ++j) acc[i][j] = (f32x4){0.f, 0.f, 0.f, 0.f};

    const int srow = tid >> 2;
    // staging: 256 threads x 8 ushorts = 2048 elems = half of 128x32; loop twice
    const int skk = (tid & 3) << 3;

    for (int k0 = 0; k0 < K; k0 += 32) {
        __syncthreads();
#pragma unroll
        for (int half = 0; half < 2; ++half) {
            int row = srow + half * 64;
            size_t ga = (size_t)(m0 + row) * K + k0 + skk;
            *(uint4*)&sAh[row * LDK + skk] = *(const uint4*)&Ahi[ga];
            *(uint4*)&sAl[row * LDK + skk] = *(const uint4*)&Alo[ga];
            size_t gb = (size_t)(n0 + row) * K + k0 + skk;
            *(uint4*)&sBh[row * LDK + skk] = *(const uint4*)&Bthi[gb];
            *(uint4*)&sBl[row * LDK + skk] = *(const uint4*)&Btlo[gb];
        }
        __syncthreads();
        bf16x8 ah[4], al[4], bh[4], bl[4];
#pragma unroll
        for (int i = 0; i < 4; ++i) {
            int r = wm * 64 + i * 16 + lrow;
            ah[i] = *(const bf16x8*)&sAh[r * LDK + lk];
            al[i] = *(const bf16x8*)&sAl[r * LDK + lk];
            int c = wn * 64 + i * 16 + lrow;
            bh[i] = *(const bf16x8*)&sBh[c * LDK + lk];
            bl[i] = *(const bf16x8*)&sBl[c * LDK + lk];
        }
#pragma unroll
        for (int i = 0; i < 4; ++i)
#pragma unroll
            for (int j = 0; j < 4; ++j) {
                acc[i][j] = __builtin_amdgcn_mfma_f32_16x16x32_bf16(ah[i], bh[j], acc[i][j], 0, 0, 0);
                acc[i][j] = __builtin_amdgcn_mfma_f32_16x16x32_bf16(ah[i], bl[j], acc[i][j], 0, 0, 0);
                acc[i][j] = __builtin_amdgcn_mfma_f32_16x16x32_bf16(al[i], bh[j], acc[i][j], 0, 0, 0);
            }
    }
    // D layout: col = lane&15, row = (lane>>4)*4 + reg
    const int drow = (lane >> 4) << 2, dcol = lane & 15;
#pragma unroll
    for (int j = 0; j < 4; ++j) {
        int col = n0 + wn * 64 + j * 16 + dcol;
        float bval = bias ? bias[col] : 0.f;
#pragma unroll
        for (int i = 0; i < 4; ++i) {
#pragma unroll
            for (int r = 0; r < 4; ++r) {
                int row = m0 + wm * 64 + i * 16 + drow + r;
                C[(size_t)row * ldc + col] = acc[i][j][r] + bval;
            }
        }
    }
}

// ---------------- bf16 split conversions ----------------
__device__ inline unsigned short f2bf(float v) {
    unsigned u = __float_as_uint(v);
    return (unsigned short)((u + 0x7FFFu + ((u >> 16) & 1u)) >> 16);
}

// A[M][K] row-major -> hi/lo planes [M][KP] (zero-padded k>=K)
__global__ void split_kernel(const float* __restrict__ in, unsigned short* __restrict__ hi,
                             unsigned short* __restrict__ lo, int M, int K, int KP) {
    int i = blockIdx.x * blockDim.x + threadIdx.x;
    if (i >= M * KP) return;
    int r = i / KP, k = i - r * KP;
    float v = (k < K) ? in[(size_t)r * K + k] : 0.f;
    unsigned short h = f2bf(v);
    float hf = __uint_as_float((unsigned)h << 16);
    hi[i] = h;
    lo[i] = f2bf(v - hf);
}

// W[K][N] row-major -> B^T hi/lo planes [N][KP]
__global__ void splitT_kernel(const float* __restrict__ W, unsigned short* __restrict__ hi,
                              unsigned short* __restrict__ lo, int K, int N, int KP) {
    int i = blockIdx.x * blockDim.x + threadIdx.x;
    if (i >= N * KP) return;
    int n = i / KP, k = i - n * KP;
    float v = (k < K) ? W[(size_t)k * N + n] : 0.f;
    unsigned short h = f2bf(v);
    float hf = __uint_as_float((unsigned)h << 16);
    hi[i] = h;
    lo[i] = f2bf(v - hf);
}

// We2 permuted view -> B^T planes [4096][128]: Bt[n][h] = We2[(n>>7)*16384 + h*128 + (n&127)]
__global__ void splitWe2_kernel(const float* __restrict__ We2, unsigned short* __restrict__ hi,
                                unsigned short* __restrict__ lo) {
    int i = blockIdx.x * blockDim.x + threadIdx.x;   // 4096*128
    if (i >= 4096 * 128) return;
    int n = i >> 7, h = i & 127;
    float v = We2[(size_t)(n >> 7) * 16384 + h * 128 + (n & 127)];
    unsigned short hh = f2bf(v);
    float hf = __uint_as_float((unsigned)hh << 16);
    hi[i] = hh;
    lo[i] = f2bf(v - hf);
}

// ---------------- generic tiled fp32 GEMM (small shapes) ----------------
__global__ __launch_bounds__(256) void gemm_kernel(
    const float* __restrict__ A, const float* __restrict__ Bm,
    const float* __restrict__ bias, const float* __restrict__ addend,
    float* __restrict__ C,
    int M, int N, int K, int lda, int ldb, int ldc, int relu)
{
    __shared__ float As[BKK][BM + 4];
    __shared__ float Bs[BKK][BN + 4];
    const int tid = threadIdx.x;
    const int tx = tid & 15, ty = tid >> 4;
    const int m0 = blockIdx.y * BM, n0 = blockIdx.x * BN;
    float acc[8][8];
#pragma unroll
    for (int i = 0; i < 8; ++i)
#pragma unroll
        for (int j = 0; j < 8; ++j) acc[i][j] = 0.f;

    for (int k0 = 0; k0 < K; k0 += BKK) {
#pragma unroll
        for (int i = 0; i < 4; ++i) {
            int e = tid + i * 256;
            int r = e >> 3, kk = e & 7;
            int gm = m0 + r, gk = k0 + kk;
            As[kk][r] = (gm < M && gk < K) ? A[(size_t)gm * lda + gk] : 0.f;
        }
#pragma unroll
        for (int i = 0; i < 4; ++i) {
            int e = tid + i * 256;
            int kk = e >> 7, c = e & 127;
            int gk = k0 + kk, gn = n0 + c;
            Bs[kk][c] = (gk < K && gn < N) ? Bm[(size_t)gk * ldb + gn] : 0.f;
        }
        __syncthreads();
#pragma unroll
        for (int kk = 0; kk < BKK; ++kk) {
            float a[8], b[8];
#pragma unroll
            for (int i = 0; i < 8; ++i) a[i] = As[kk][ty * 8 + i];
#pragma unroll
            for (int j = 0; j < 8; ++j) b[j] = Bs[kk][tx * 8 + j];
#pragma unroll
            for (int i = 0; i < 8; ++i)
#pragma unroll
                for (int j = 0; j < 8; ++j)
                    acc[i][j] = fmaf(a[i], b[j], acc[i][j]);
        }
        __syncthreads();
    }
#pragma unroll
    for (int i = 0; i < 8; ++i) {
        int gm = m0 + ty * 8 + i;
        if (gm >= M) continue;
#pragma unroll
        for (int j = 0; j < 8; ++j) {
            int gn = n0 + tx * 8 + j;
            if (gn >= N) continue;
            float val = acc[i][j];
            if (bias)   val += bias[gn];
            if (addend) val += addend[(size_t)gm * ldc + gn];
            if (relu)   val = fmaxf(val, 0.f);
            C[(size_t)gm * ldc + gn] = val;
        }
    }
}

// ---------------- elementwise / graph kernels ----------------
__global__ void fill_kernel(float* __restrict__ p, float v, int n) {
    int i = blockIdx.x * blockDim.x + threadIdx.x;
    if (i < n) p[i] = v;
}

__global__ void fill_int_kernel(int* __restrict__ p, int v, int n) {
    int i = blockIdx.x * blockDim.x + threadIdx.x;
    if (i < n) p[i] = v;
}

__global__ void hist_kernel(const int* __restrict__ dst, int* __restrict__ deg, int E) {
    int i = blockIdx.x * blockDim.x + threadIdx.x;
    if (i < E) atomicAdd(&deg[dst[i]], 1);
}

__global__ void dinv_kernel(const int* __restrict__ deg, float* __restrict__ dinv, int n) {
    int i = blockIdx.x * blockDim.x + threadIdx.x;
    if (i < n) dinv[i] = rsqrtf((float)deg[i] + 1.0f);   // +1 for self loop
}

__global__ void scan_block_kernel(const int* __restrict__ deg, int* __restrict__ rp,
                                  int* __restrict__ bsum) {
    __shared__ int s[256];
    int t = threadIdx.x;
    int i = blockIdx.x * 256 + t;
    int v = deg[i];
    s[t] = v;
    __syncthreads();
    int x = v;
    for (int off = 1; off < 256; off <<= 1) {
        int y = (t >= off) ? s[t - off] : 0;
        __syncthreads();
        x += y; s[t] = x;
        __syncthreads();
    }
    rp[i] = x - v;
    if (t == 255) bsum[blockIdx.x] = x;
}

__global__ void scan_bsum_kernel(int* __restrict__ bsum, int nb) {
    __shared__ int s[512];
    int t = threadIdx.x;
    int v = (t < nb) ? bsum[t] : 0;
    s[t] = v;
    __syncthreads();
    int x = v;
    for (int off = 1; off < 512; off <<= 1) {
        int y = (t >= off) ? s[t - off] : 0;
        __syncthreads();
        x += y; s[t] = x;
        __syncthreads();
    }
    if (t < nb) bsum[t] = x - v;
}

__global__ void add_offsets_kernel(int* __restrict__ rp, const int* __restrict__ bsum,
                                   int* __restrict__ cursor) {
    int i = blockIdx.x * 256 + threadIdx.x;
    int v = rp[i] + bsum[blockIdx.x];
    rp[i] = v;
    cursor[i] = v;
}

__global__ void csr_fill_kernel(const int* __restrict__ src, const int* __restrict__ dst,
                                const float* __restrict__ dinv, int* __restrict__ cursor,
                                int* __restrict__ ssrc, float* __restrict__ sw, int E) {
    int e = blockIdx.x * blockDim.x + threadIdx.x;
    if (e >= E) return;
    int s = src[e], d = dst[e];
    int pos = atomicAdd(&cursor[d], 1);
    ssrc[pos] = s;
    sw[pos] = dinv[s] * dinv[d];
}

__global__ void gather_kernel(const float* __restrict__ h, const int* __restrict__ rp,
                              const int* __restrict__ rend, const int* __restrict__ ssrc,
                              const float* __restrict__ sw, const float* __restrict__ dinv,
                              const float* __restrict__ bias, float* __restrict__ out) {
    int t = blockIdx.x * blockDim.x + threadIdx.x;
    if (t >= NNODES * 32) return;
    int n = t >> 5, c = t & 31;
    float w0 = dinv[n]; w0 *= w0;
    float4 acc = reinterpret_cast<const float4*>(h + (size_t)n * HD)[c];
    acc.x *= w0; acc.y *= w0; acc.z *= w0; acc.w *= w0;
    int beg = rp[n], end = rend[n];
    for (int e = beg; e < end; ++e) {
        int s = ssrc[e];
        float w = sw[e];
        float4 v = reinterpret_cast<const float4*>(h + (size_t)s * HD)[c];
        acc.x += v.x * w; acc.y += v.y * w; acc.z += v.z * w; acc.w += v.w * w;
    }
    float4 bb = reinterpret_cast<const float4*>(bias)[c];
    acc.x = fmaxf(acc.x + bb.x, 0.f);
    acc.y = fmaxf(acc.y + bb.y, 0.f);
    acc.z = fmaxf(acc.z + bb.z, 0.f);
    acc.w = fmaxf(acc.w + bb.w, 0.f);
    reinterpret_cast<float4*>(out)[t] = acc;
}

__global__ void pool_kernel(const float* __restrict__ x, float* __restrict__ xg) {
    int i = blockIdx.x * blockDim.x + threadIdx.x;   // NB*HD
    if (i >= NB * HD) return;
    int b = i >> 7, c = i & 127;
    const float* p = x + (size_t)b * 20 * HD + c;
    float s = 0.f;
#pragma unroll
    for (int r = 0; r < 20; ++r) s += p[r * HD];
    xg[i] = s * 0.05f;
}

__global__ void node_feat_kernel(const float* __restrict__ xg, const float* __restrict__ ap,
                                 const float* __restrict__ bp, const float* __restrict__ svt,
                                 const float* __restrict__ sut, float* __restrict__ nodef) {
    int i = blockIdx.x * blockDim.x + threadIdx.x;   // 2*NB*131
    if (i >= 2 * NB * 131) return;
    int row = i / 131, col = i - row * 131;
    float v;
    if (col < 128) v = xg[(size_t)row * 128 + col];
    else {
        int g = (row < NB) ? row : row - NB;
        if (col == 128)      v = ap[g];
        else if (col == 129) v = bp[g];
        else                 v = (row < NB) ? svt[g] : sut[g];
    }
    nodef[i] = v;
}

__global__ void edge_t_kernel(const float* __restrict__ svhb, const float* __restrict__ suhb,
                              const float* __restrict__ We1, const float* __restrict__ be1,
                              float* __restrict__ tsv, float* __restrict__ tsu) {
    int i = blockIdx.x * blockDim.x + threadIdx.x;   // NB*32
    if (i >= NB * 32) return;
    int g = i >> 5, k = i & 31;
    tsv[i] = fmaxf(svhb[g] * We1[k] + be1[k], 0.f);
    tsu[i] = fmaxf(suhb[g] * We1[k] + be1[k], 0.f);
}

__global__ void assembly_kernel(const float* __restrict__ C, const float* __restrict__ v,
                                const float* __restrict__ tsv, const float* __restrict__ tsu,
                                float* __restrict__ aggr) {
    int i = blockIdx.x;      // graph
    int o = threadIdx.x;     // 0..127
    __shared__ float sv[32], su[32];
    if (o < 32)       sv[o] = tsv[(size_t)i * 32 + o];
    else if (o < 64)  su[o - 32] = tsu[(size_t)i * 32 + (o - 32)];
    __syncthreads();
    const float* Ci = C + (size_t)i * 4096;
    const float* Cs = C + (size_t)(NB + i) * 4096;
    float ai = 0.f, as = 0.f;
#pragma unroll
    for (int k = 0; k < 32; ++k) {
        float ci = Ci[k * 128 + o], cs = Cs[k * 128 + o];
        ai += sv[k] * (ci + cs);
        as += sv[k] * ci + su[k] * cs;
    }
    float vv = v[(size_t)i * 128 + o] + v[(size_t)(NB + i) * 128 + o];
    aggr[(size_t)i * 128 + o]        = ai + vv;
    aggr[(size_t)(NB + i) * 128 + o] = as + vv;
}

__global__ void gru_kernel(const float* __restrict__ gi, const float* __restrict__ gh,
                           const float* __restrict__ h0, float* __restrict__ hout) {
    int i = blockIdx.x * blockDim.x + threadIdx.x;   // 2*NB*128
    if (i >= 2 * NB * HD) return;
    int n = i >> 7, c = i & 127;
    const float* gin = gi + (size_t)n * 384;
    const float* ghn = gh + (size_t)n * 384;
    float r = gin[c] + ghn[c];
    float z = gin[128 + c] + ghn[128 + c];
    r = 1.f / (1.f + expf(-r));
    z = 1.f / (1.f + expf(-z));
    float nn = tanhf(gin[256 + c] + r * ghn[256 + c]);
    hout[i] = (1.f - z) * nn + z * h0[i];
}

__global__ void xgm_kernel(const float* __restrict__ h, const float* __restrict__ Tx,
                           float* __restrict__ xgm) {
    int i = blockIdx.x * blockDim.x + threadIdx.x;   // NB*257
    if (i >= NB * 257) return;
    int row = i / 257, col = i - row * 257;
    float v;
    if (col < 128)      v = h[(size_t)row * 128 + col];
    else if (col < 256) v = h[(size_t)(NB + row) * 128 + (col - 128)];
    else                v = (Tx[row] + 60.f) * (1.f / 349.3f);
    xgm[i] = v;
}

// ---------------- launcher ----------------
extern "C" void kernel_launch(void* const* d_in, const int* in_sizes, int n_in,
                              void* d_out, int out_size, void* d_ws, size_t ws_size,
                              hipStream_t stream)
{
    const float* sv_x   = (const float*)d_in[0];
    const int*   sv_ei  = (const int*)d_in[1];
    const float* su_x   = (const float*)d_in[3];
    const int*   su_ei  = (const int*)d_in[4];
    const float* ap     = (const float*)d_in[6];
    const float* bp     = (const float*)d_in[7];
    const float* sv_top = (const float*)d_in[8];
    const float* su_top = (const float*)d_in[9];
    const float* sv_hb  = (const float*)d_in[10];
    const float* su_hb  = (const float*)d_in[11];
    const float* T_x    = (const float*)d_in[12];
    const float* W_gcn1 = (const float*)d_in[13];
    const float* b_gcn1 = (const float*)d_in[14];
    const float* W_gcn2 = (const float*)d_in[15];
    const float* b_gcn2 = (const float*)d_in[16];
    const float* Wp     = (const float*)d_in[17];
    const float* bp_pr  = (const float*)d_in[18];
    const float* We1    = (const float*)d_in[19];
    const float* be1    = (const float*)d_in[20];
    const float* We2    = (const float*)d_in[21];
    const float* be2    = (const float*)d_in[22];
    const float* W_root = (const float*)d_in[23];
    const float* b_nn   = (const float*)d_in[24];
    const float* W_ih   = (const float*)d_in[25];
    const float* W_hh   = (const float*)d_in[26];
    const float* b_ih   = (const float*)d_in[27];
    const float* b_hh   = (const float*)d_in[28];
    const float* Wm1    = (const float*)d_in[29];
    const float* bm1    = (const float*)d_in[30];
    const float* Wm2    = (const float*)d_in[31];
    const float* bm2    = (const float*)d_in[32];
    const float* Wm3    = (const float*)d_in[33];
    const float* bm3    = (const float*)d_in[34];
    float* out = (float*)d_out;

    float* ws = (float*)d_ws;
    const size_t BIGF = (size_t)2 * NB * 4096;      // 33,554,432 floats
    // big region phase 1 (GCN): h_tmp, h_agg, A-split planes
    float* h_tmp = ws;                                         // 10,485,760
    float* h_agg = ws + 10485760;                              // 10,485,760
    unsigned short* asph = (unsigned short*)(ws + 20971520);   // 81920x128 ushorts
    unsigned short* aspl = (unsigned short*)(ws + 26214400);
    // big region phase 2 (MPNN): Cbuf
    float* Cbuf  = ws;
    // big region phase 3 (post-assembly): GRU/MLP temporaries
    float* gi    = ws;                  // 8192x384
    float* gh    = ws + 3145728;        // 8192x384
    float* xgm   = ws + 6291456;        // 4096x257
    float* o1    = ws + 7344128;        // 4096x256
    float* o2    = ws + 8392704;        // 4096x128
    // persistent small region
    float* p = ws + BIGF;
    float* xg    = p; p += (size_t)2 * NB * HD;
    float* nodef = p; p += (size_t)2 * NB * 131;
    float* h0    = p; p += (size_t)2 * NB * HD;
    float* tsv   = p; p += (size_t)NB * 32;
    float* tsu   = p; p += (size_t)NB * 32;
    float* vbuf  = p; p += (size_t)2 * NB * HD;
    float* aggrb = p; p += (size_t)2 * NB * HD;
    float* nf    = p; p += (size_t)2 * NB * HD;
    float* hout  = p; p += (size_t)2 * NB * HD;
    float* dinv  = p; p += NNODES;
    int* deg_i   = (int*)p; p += NNODES;
    int* row_ptr = (int*)p; p += NNODES;
    int* cursor  = (int*)p; p += NNODES;
    int* bsum    = (int*)p; p += 512;
    int* ssrc    = (int*)p; p += NEDGES;
    float* sw    = p; p += NEDGES;
    // split planes (ushort buffers, sizes in float units)
    unsigned short* h0sph = (unsigned short*)p; p += 524288;
    unsigned short* h0spl = (unsigned short*)p; p += 524288;
    unsigned short* nfsph = (unsigned short*)p; p += 524288;
    unsigned short* nfspl = (unsigned short*)p; p += 524288;
    unsigned short* w1th  = (unsigned short*)p; p += 6144;   // 128x96
    unsigned short* w1tl  = (unsigned short*)p; p += 6144;
    unsigned short* w2th  = (unsigned short*)p; p += 8192;   // 128x128
    unsigned short* w2tl  = (unsigned short*)p; p += 8192;
    unsigned short* we2th = (unsigned short*)p; p += 262144; // 4096x128
    unsigned short* we2tl = (unsigned short*)p; p += 262144;
    unsigned short* wihh  = (unsigned short*)p; p += 24576;  // 384x128
    unsigned short* wihl  = (unsigned short*)p; p += 24576;
    unsigned short* whhh  = (unsigned short*)p; p += 24576;
    unsigned short* whhl  = (unsigned short*)p; p += 24576;
    size_t need_bytes = (size_t)(p - ws) * sizeof(float);
    if (ws_size < need_bytes) {
        fill_kernel<<<(out_size + 255) / 256, 256, 0, stream>>>(out, -1.0e6f, out_size);
        return;
    }

    auto gemm = [&](const float* A, const float* Bmat, const float* bias, const float* add,
                    float* Cc, int M, int Nn, int K, int lda, int ldb, int ldc, int relu) {
        dim3 g((Nn + BN - 1) / BN, (M + BM - 1) / BM);
        gemm_kernel<<<g, 256, 0, stream>>>(A, Bmat, bias, add, Cc, M, Nn, K, lda, ldb, ldc, relu);
    };
    auto mgemm = [&](const unsigned short* Ah, const unsigned short* Al,
                     const unsigned short* Bh, const unsigned short* Bl,
                     const float* bias, float* Cc, int M, int Nn, int K, int ldc) {
        dim3 g(Nn / 128, M / 128);
        mfma_gemm_kernel<<<g, 256, 0, stream>>>(Ah, Al, Bh, Bl, bias, Cc, M, Nn, K, ldc);
    };

    // weight splits (recomputed every call; ws is re-poisoned each call)
    splitT_kernel<<<(128 * 96 + 255) / 256, 256, 0, stream>>>(W_gcn1, w1th, w1tl, 74, 128, 96);
    splitT_kernel<<<(128 * 128 + 255) / 256, 256, 0, stream>>>(W_gcn2, w2th, w2tl, 128, 128, 128);
    splitWe2_kernel<<<(4096 * 128 + 255) / 256, 256, 0, stream>>>(We2, we2th, we2tl);
    split_kernel<<<(384 * 128 + 255) / 256, 256, 0, stream>>>(W_ih, wihh, wihl, 384, 128, 128);
    split_kernel<<<(384 * 128 + 255) / 256, 256, 0, stream>>>(W_hh, whhh, whhl, 384, 128, 128);

    auto run_gcn = [&](const float* x, const int* ei, float* xg_out) {
        const int* src = ei;
        const int* dst = ei + NEDGES;
        // CSR build
        fill_int_kernel<<<(NNODES + 255) / 256, 256, 0, stream>>>(deg_i, 0, NNODES);
        hist_kernel<<<(NEDGES + 255) / 256, 256, 0, stream>>>(dst, deg_i, NEDGES);
        dinv_kernel<<<(NNODES + 255) / 256, 256, 0, stream>>>(deg_i, dinv, NNODES);
        scan_block_kernel<<<NNODES / 256, 256, 0, stream>>>(deg_i, row_ptr, bsum);
        scan_bsum_kernel<<<1, 512, 0, stream>>>(bsum, NNODES / 256);
        add_offsets_kernel<<<NNODES / 256, 256, 0, stream>>>(row_ptr, bsum, cursor);
        csr_fill_kernel<<<(NEDGES + 255) / 256, 256, 0, stream>>>(src, dst, dinv, cursor, ssrc, sw, NEDGES);
        // conv1: h_tmp = x @ W_gcn1 (MFMA split-bf16, K=74 padded to 96)
        split_kernel<<<(NNODES * 96 + 255) / 256, 256, 0, stream>>>(x, asph, aspl, NNODES, 74, 96);
        mgemm(asph, aspl, w1th, w1tl, nullptr, h_tmp, NNODES, 128, 96, 128);
        gather_kernel<<<(NNODES * 32 + 255) / 256, 256, 0, stream>>>(
            h_tmp, row_ptr, cursor, ssrc, sw, dinv, b_gcn1, h_agg);
        // conv2: h_tmp = x1 @ W_gcn2
        split_kernel<<<(NNODES * 128 + 255) / 256, 256, 0, stream>>>(h_agg, asph, aspl, NNODES, 128, 128);
        mgemm(asph, aspl, w2th, w2tl, nullptr, h_tmp, NNODES, 128, 128, 128);
        gather_kernel<<<(NNODES * 32 + 255) / 256, 256, 0, stream>>>(
            h_tmp, row_ptr, cursor, ssrc, sw, dinv, b_gcn2, h_agg);
        pool_kernel<<<(NB * HD + 255) / 256, 256, 0, stream>>>(h_agg, xg_out);
    };

    run_gcn(sv_x, sv_ei, xg);
    run_gcn(su_x, su_ei, xg + (size_t)NB * HD);

    // MPNN
    node_feat_kernel<<<(2 * NB * 131 + 255) / 256, 256, 0, stream>>>(xg, ap, bp, sv_top, su_top, nodef);
    gemm(nodef, Wp, bp_pr, nullptr, h0, 2 * NB, HD, 131, 131, HD, HD, 1);
    edge_t_kernel<<<(NB * 32 + 255) / 256, 256, 0, stream>>>(sv_hb, su_hb, We1, be1, tsv, tsu);
    // Cbuf = h0 @ We2-view (MFMA split-bf16)
    split_kernel<<<(2 * NB * 128 + 255) / 256, 256, 0, stream>>>(h0, h0sph, h0spl, 2 * NB, 128, 128);
    mgemm(h0sph, h0spl, we2th, we2tl, nullptr, Cbuf, 2 * NB, 4096, 128, 4096);
    gemm(h0, be2, nullptr, nullptr, vbuf, 2 * NB, HD, HD, HD, HD, HD, 0);
    assembly_kernel<<<NB, 128, 0, stream>>>(Cbuf, vbuf, tsv, tsu, aggrb);
    // nf = relu(h0 @ W_root + aggr + b_nn)
    gemm(h0, W_root, b_nn, aggrb, nf, 2 * NB, HD, HD, HD, HD, HD, 1);
    // GRU gates (MFMA split-bf16, B^T = W_ih / W_hh natural layout)
    split_kernel<<<(2 * NB * 128 + 255) / 256, 256, 0, stream>>>(nf, nfsph, nfspl, 2 * NB, 128, 128);
    mgemm(nfsph, nfspl, wihh, wihl, b_ih, gi, 2 * NB, 384, 128, 384);
    mgemm(h0sph, h0spl, whhh, whhl, b_hh, gh, 2 * NB, 384, 128, 384);
    gru_kernel<<<(2 * NB * HD + 255) / 256, 256, 0, stream>>>(gi, gh, h0, hout);
    // output MLP
    xgm_kernel<<<(NB * 257 + 255) / 256, 256, 0, stream>>>(hout, T_x, xgm);
    gemm(xgm, Wm1, bm1, nullptr, o1, NB, 256, 257, 257, 256, 256, 1);
    gemm(o1, Wm2, bm2, nullptr, o2, NB, HD, 256, 256, HD, HD, 1);
    gemm(o2, Wm3, bm3, nullptr, out, NB, 1, HD, HD, 1, 1, 0);
}

// Round 9
// 678.581 us; speedup vs baseline: 3.9548x; 1.5550x over previous
//
#include <hip/hip_runtime.h>
#include <math.h>

#define NNODES 81920
#define NEDGES 163840
#define NB     4096
#define HD     128

typedef __attribute__((ext_vector_type(8))) short bf16x8;
typedef __attribute__((ext_vector_type(4))) float f32x4;
typedef __attribute__((ext_vector_type(4))) unsigned short us4;

#define LDK 40  // LDS k-stride in ushorts (80B rows: 20-bank stride, <=2-way conflicts)

__device__ inline unsigned short f2bf(float v) {
    unsigned u = __float_as_uint(v);
    return (unsigned short)((u + 0x7FFFu + ((u >> 16) & 1u)) >> 16);
}

// ---------------- split-bf16 MFMA GEMM ----------------
// C = A*B (+bias) (+addend) (relu), A as hi/lo bf16 planes [M][K] row-major,
// B as B^T hi/lo planes [N][K] row-major. K mult of 32; M,N mult of 128 (N: 384 ok).
// Outputs: Cf (fp32) and/or Chi/Clo (split planes), any may be null.
__global__ __launch_bounds__(256) void mfma_gemm_kernel(
    const unsigned short* __restrict__ Ahi, const unsigned short* __restrict__ Alo,
    const unsigned short* __restrict__ Bthi, const unsigned short* __restrict__ Btlo,
    const float* __restrict__ bias, const float* __restrict__ addend,
    float* __restrict__ Cf, unsigned short* __restrict__ Chi, unsigned short* __restrict__ Clo,
    int M, int N, int K, int ldc, int relu)
{
    __shared__ unsigned short sAh[128 * LDK], sAl[128 * LDK];
    __shared__ unsigned short sBh[128 * LDK], sBl[128 * LDK];
    const int tid  = threadIdx.x;
    const int lane = tid & 63;
    const int wid  = tid >> 6;
    const int wm   = wid >> 1, wn = wid & 1;       // 2x2 waves of 64x64
    const int m0   = blockIdx.y * 128, n0 = blockIdx.x * 128;
    const int lrow = lane & 15;
    const int lk   = (lane >> 4) << 3;             // k offset 0/8/16/24

    f32x4 acc[4][4];
#pragma unroll
    for (int i = 0; i < 4; ++i)
#pragma unroll
        for (int j = 0; j < 4; ++j) acc[i][j] = (f32x4){0.f, 0.f, 0.f, 0.f};

    const int srow = tid >> 2;
    const int skk = (tid & 3) << 3;

    for (int k0 = 0; k0 < K; k0 += 32) {
        __syncthreads();
#pragma unroll
        for (int half = 0; half < 2; ++half) {
            int row = srow + half * 64;
            size_t ga = (size_t)(m0 + row) * K + k0 + skk;
            *(uint4*)&sAh[row * LDK + skk] = *(const uint4*)&Ahi[ga];
            *(uint4*)&sAl[row * LDK + skk] = *(const uint4*)&Alo[ga];
            size_t gb = (size_t)(n0 + row) * K + k0 + skk;
            *(uint4*)&sBh[row * LDK + skk] = *(const uint4*)&Bthi[gb];
            *(uint4*)&sBl[row * LDK + skk] = *(const uint4*)&Btlo[gb];
        }
        __syncthreads();
        bf16x8 ah[4], al[4], bh[4], bl[4];
#pragma unroll
        for (int i = 0; i < 4; ++i) {
            int r = wm * 64 + i * 16 + lrow;
            ah[i] = *(const bf16x8*)&sAh[r * LDK + lk];
            al[i] = *(const bf16x8*)&sAl[r * LDK + lk];
            int c = wn * 64 + i * 16 + lrow;
            bh[i] = *(const bf16x8*)&sBh[c * LDK + lk];
            bl[i] = *(const bf16x8*)&sBl[c * LDK + lk];
        }
#pragma unroll
        for (int i = 0; i < 4; ++i)
#pragma unroll
            for (int j = 0; j < 4; ++j) {
                acc[i][j] = __builtin_amdgcn_mfma_f32_16x16x32_bf16(ah[i], bh[j], acc[i][j], 0, 0, 0);
                acc[i][j] = __builtin_amdgcn_mfma_f32_16x16x32_bf16(ah[i], bl[j], acc[i][j], 0, 0, 0);
                acc[i][j] = __builtin_amdgcn_mfma_f32_16x16x32_bf16(al[i], bh[j], acc[i][j], 0, 0, 0);
            }
    }
    // D layout: col = lane&15, row = (lane>>4)*4 + reg
    const int drow = (lane >> 4) << 2, dcol = lane & 15;
#pragma unroll
    for (int j = 0; j < 4; ++j) {
        int col = n0 + wn * 64 + j * 16 + dcol;
        float bval = bias ? bias[col] : 0.f;
#pragma unroll
        for (int i = 0; i < 4; ++i) {
#pragma unroll
            for (int r = 0; r < 4; ++r) {
                int row = m0 + wm * 64 + i * 16 + drow + r;
                size_t idx = (size_t)row * ldc + col;
                float val = acc[i][j][r] + bval;
                if (addend) val += addend[idx];
                if (relu)   val = fmaxf(val, 0.f);
                if (Cf) Cf[idx] = val;
                if (Chi) {
                    unsigned short h = f2bf(val);
                    Chi[idx] = h;
                    Clo[idx] = f2bf(val - __uint_as_float((unsigned)h << 16));
                }
            }
        }
    }
}

// ---------------- bf16 split conversions ----------------
// A[M][K] row-major -> hi/lo planes [M][KP] (zero-padded k>=K)
__global__ void split_kernel(const float* __restrict__ in, unsigned short* __restrict__ hi,
                             unsigned short* __restrict__ lo, int M, int K, int KP) {
    int i = blockIdx.x * blockDim.x + threadIdx.x;
    if (i >= M * KP) return;
    int r = i / KP, k = i - r * KP;
    float v = (k < K) ? in[(size_t)r * K + k] : 0.f;
    unsigned short h = f2bf(v);
    hi[i] = h;
    lo[i] = f2bf(v - __uint_as_float((unsigned)h << 16));
}

// W[K][N] row-major -> B^T hi/lo planes [N][KP]
__global__ void splitT_kernel(const float* __restrict__ W, unsigned short* __restrict__ hi,
                              unsigned short* __restrict__ lo, int K, int N, int KP) {
    int i = blockIdx.x * blockDim.x + threadIdx.x;
    if (i >= N * KP) return;
    int n = i / KP, k = i - n * KP;
    float v = (k < K) ? W[(size_t)k * N + n] : 0.f;
    unsigned short h = f2bf(v);
    hi[i] = h;
    lo[i] = f2bf(v - __uint_as_float((unsigned)h << 16));
}

// We2 permuted view -> B^T planes [4096][128]: Bt[n][h] = We2[(n>>7)*16384 + h*128 + (n&127)]
__global__ void splitWe2_kernel(const float* __restrict__ We2, unsigned short* __restrict__ hi,
                                unsigned short* __restrict__ lo) {
    int i = blockIdx.x * blockDim.x + threadIdx.x;   // 4096*128
    if (i >= 4096 * 128) return;
    int n = i >> 7, h = i & 127;
    float v = We2[(size_t)(n >> 7) * 16384 + h * 128 + (n & 127)];
    unsigned short hh = f2bf(v);
    hi[i] = hh;
    lo[i] = f2bf(v - __uint_as_float((unsigned)hh << 16));
}

// ---------------- elementwise / graph kernels ----------------
__global__ void fill_kernel(float* __restrict__ p, float v, int n) {
    int i = blockIdx.x * blockDim.x + threadIdx.x;
    if (i < n) p[i] = v;
}

__global__ void fill_int_kernel(int* __restrict__ p, int v, int n) {
    int i = blockIdx.x * blockDim.x + threadIdx.x;
    if (i < n) p[i] = v;
}

__global__ void hist_kernel(const int* __restrict__ dst, int* __restrict__ deg, int E) {
    int i = blockIdx.x * blockDim.x + threadIdx.x;
    if (i < E) atomicAdd(&deg[dst[i]], 1);
}

__global__ void dinv_kernel(const int* __restrict__ deg, float* __restrict__ dinv, int n) {
    int i = blockIdx.x * blockDim.x + threadIdx.x;
    if (i < n) dinv[i] = rsqrtf((float)deg[i] + 1.0f);   // +1 for self loop
}

__global__ void scan_block_kernel(const int* __restrict__ deg, int* __restrict__ rp,
                                  int* __restrict__ bsum) {
    __shared__ int s[256];
    int t = threadIdx.x;
    int i = blockIdx.x * 256 + t;
    int v = deg[i];
    s[t] = v;
    __syncthreads();
    int x = v;
    for (int off = 1; off < 256; off <<= 1) {
        int y = (t >= off) ? s[t - off] : 0;
        __syncthreads();
        x += y; s[t] = x;
        __syncthreads();
    }
    rp[i] = x - v;
    if (t == 255) bsum[blockIdx.x] = x;
}

__global__ void scan_bsum_kernel(int* __restrict__ bsum, int nb) {
    __shared__ int s[512];
    int t = threadIdx.x;
    int v = (t < nb) ? bsum[t] : 0;
    s[t] = v;
    __syncthreads();
    int x = v;
    for (int off = 1; off < 512; off <<= 1) {
        int y = (t >= off) ? s[t - off] : 0;
        __syncthreads();
        x += y; s[t] = x;
        __syncthreads();
    }
    if (t < nb) bsum[t] = x - v;
}

__global__ void add_offsets_kernel(int* __restrict__ rp, const int* __restrict__ bsum,
                                   int* __restrict__ cursor) {
    int i = blockIdx.x * 256 + threadIdx.x;
    int v = rp[i] + bsum[blockIdx.x];
    rp[i] = v;
    cursor[i] = v;
}

__global__ void csr_fill_kernel(const int* __restrict__ src, const int* __restrict__ dst,
                                const float* __restrict__ dinv, int* __restrict__ cursor,
                                int* __restrict__ ssrc, float* __restrict__ sw, int E) {
    int e = blockIdx.x * blockDim.x + threadIdx.x;
    if (e >= E) return;
    int s = src[e], d = dst[e];
    int pos = atomicAdd(&cursor[d], 1);
    ssrc[pos] = s;
    sw[pos] = dinv[s] * dinv[d];
}

// fused GCN aggregation: r = relu( h[n]*dinv[n]^2 + sum_e h[src_e]*w_e + bias )
// mode 0: write fp32 out; mode 1: write split-bf16 planes ohi/olo
__global__ void gather_kernel(const float* __restrict__ h, const int* __restrict__ rp,
                              const int* __restrict__ rend, const int* __restrict__ ssrc,
                              const float* __restrict__ sw, const float* __restrict__ dinv,
                              const float* __restrict__ bias, float* __restrict__ out,
                              unsigned short* __restrict__ ohi, unsigned short* __restrict__ olo,
                              int mode) {
    int t = blockIdx.x * blockDim.x + threadIdx.x;
    if (t >= NNODES * 32) return;
    int n = t >> 5, c = t & 31;
    float w0 = dinv[n]; w0 *= w0;
    float4 acc = reinterpret_cast<const float4*>(h + (size_t)n * HD)[c];
    acc.x *= w0; acc.y *= w0; acc.z *= w0; acc.w *= w0;
    int beg = rp[n], end = rend[n];
    for (int e = beg; e < end; ++e) {
        int s = ssrc[e];
        float w = sw[e];
        float4 v = reinterpret_cast<const float4*>(h + (size_t)s * HD)[c];
        acc.x += v.x * w; acc.y += v.y * w; acc.z += v.z * w; acc.w += v.w * w;
    }
    float4 bb = reinterpret_cast<const float4*>(bias)[c];
    acc.x = fmaxf(acc.x + bb.x, 0.f);
    acc.y = fmaxf(acc.y + bb.y, 0.f);
    acc.z = fmaxf(acc.z + bb.z, 0.f);
    acc.w = fmaxf(acc.w + bb.w, 0.f);
    if (mode == 0) {
        reinterpret_cast<float4*>(out)[t] = acc;
    } else {
        float vals[4] = {acc.x, acc.y, acc.z, acc.w};
        us4 hv, lv;
#pragma unroll
        for (int k = 0; k < 4; ++k) {
            unsigned short hh = f2bf(vals[k]);
            hv[k] = hh;
            lv[k] = f2bf(vals[k] - __uint_as_float((unsigned)hh << 16));
        }
        *(us4*)&ohi[(size_t)n * HD + c * 4] = hv;
        *(us4*)&olo[(size_t)n * HD + c * 4] = lv;
    }
}

__global__ void pool_kernel(const float* __restrict__ x, float* __restrict__ xg) {
    int i = blockIdx.x * blockDim.x + threadIdx.x;   // NB*HD
    if (i >= NB * HD) return;
    int b = i >> 7, c = i & 127;
    const float* p = x + (size_t)b * 20 * HD + c;
    float s = 0.f;
#pragma unroll
    for (int r = 0; r < 20; ++r) s += p[r * HD];
    xg[i] = s * 0.05f;
}

// node_feat -> split planes [2NB][160] (cols: 0-127 xg, 128 ap, 129 bp, 130 topopsa, pad 0)
__global__ void node_feat_split_kernel(const float* __restrict__ xg, const float* __restrict__ ap,
                                       const float* __restrict__ bp, const float* __restrict__ svt,
                                       const float* __restrict__ sut,
                                       unsigned short* __restrict__ hi, unsigned short* __restrict__ lo) {
    int i = blockIdx.x * blockDim.x + threadIdx.x;   // 2*NB*160
    if (i >= 2 * NB * 160) return;
    int row = i / 160, col = i - row * 160;
    float v = 0.f;
    if (col < 128) v = xg[(size_t)row * 128 + col];
    else if (col < 131) {
        int g = (row < NB) ? row : row - NB;
        if (col == 128)      v = ap[g];
        else if (col == 129) v = bp[g];
        else                 v = (row < NB) ? svt[g] : sut[g];
    }
    unsigned short h = f2bf(v);
    hi[i] = h;
    lo[i] = f2bf(v - __uint_as_float((unsigned)h << 16));
}

__global__ void edge_t_kernel(const float* __restrict__ svhb, const float* __restrict__ suhb,
                              const float* __restrict__ We1, const float* __restrict__ be1,
                              float* __restrict__ tsv, float* __restrict__ tsu) {
    int i = blockIdx.x * blockDim.x + threadIdx.x;   // NB*32
    if (i >= NB * 32) return;
    int g = i >> 5, k = i & 31;
    tsv[i] = fmaxf(svhb[g] * We1[k] + be1[k], 0.f);
    tsu[i] = fmaxf(suhb[g] * We1[k] + be1[k], 0.f);
}

__global__ void assembly_kernel(const float* __restrict__ C, const float* __restrict__ v,
                                const float* __restrict__ tsv, const float* __restrict__ tsu,
                                float* __restrict__ aggr) {
    int i = blockIdx.x;      // graph
    int o = threadIdx.x;     // 0..127
    __shared__ float sv[32], su[32];
    if (o < 32)       sv[o] = tsv[(size_t)i * 32 + o];
    else if (o < 64)  su[o - 32] = tsu[(size_t)i * 32 + (o - 32)];
    __syncthreads();
    const float* Ci = C + (size_t)i * 4096;
    const float* Cs = C + (size_t)(NB + i) * 4096;
    float ai = 0.f, as = 0.f;
#pragma unroll
    for (int k = 0; k < 32; ++k) {
        float ci = Ci[k * 128 + o], cs = Cs[k * 128 + o];
        ai += sv[k] * (ci + cs);
        as += sv[k] * ci + su[k] * cs;
    }
    float vv = v[(size_t)i * 128 + o] + v[(size_t)(NB + i) * 128 + o];
    aggr[(size_t)i * 128 + o]        = ai + vv;
    aggr[(size_t)(NB + i) * 128 + o] = as + vv;
}

__global__ void gru_kernel(const float* __restrict__ gi, const float* __restrict__ gh,
                           const float* __restrict__ h0, float* __restrict__ hout) {
    int i = blockIdx.x * blockDim.x + threadIdx.x;   // 2*NB*128
    if (i >= 2 * NB * HD) return;
    int n = i >> 7, c = i & 127;
    const float* gin = gi + (size_t)n * 384;
    const float* ghn = gh + (size_t)n * 384;
    float r = gin[c] + ghn[c];
    float z = gin[128 + c] + ghn[128 + c];
    r = 1.f / (1.f + expf(-r));
    z = 1.f / (1.f + expf(-z));
    float nn = tanhf(gin[256 + c] + r * ghn[256 + c]);
    hout[i] = (1.f - z) * nn + z * h0[i];
}

// xgm (cols 0-127 h[:B], 128-255 h[B:], 256 T_norm, pad to 288) -> split planes
__global__ void xgm_split_kernel(const float* __restrict__ h, const float* __restrict__ Tx,
                                 unsigned short* __restrict__ hi, unsigned short* __restrict__ lo) {
    int i = blockIdx.x * blockDim.x + threadIdx.x;   // NB*288
    if (i >= NB * 288) return;
    int row = i / 288, col = i - row * 288;
    float v = 0.f;
    if (col < 128)      v = h[(size_t)row * 128 + col];
    else if (col < 256) v = h[(size_t)(NB + row) * 128 + (col - 128)];
    else if (col == 256) v = (Tx[row] + 60.f) * (1.f / 349.3f);
    unsigned short hh = f2bf(v);
    hi[i] = hh;
    lo[i] = f2bf(v - __uint_as_float((unsigned)hh << 16));
}

// out[r] = dot(o2[r,:], Wm3) + bm3, one wave per row
__global__ void matvec_kernel(const float* __restrict__ o2, const float* __restrict__ Wm3,
                              const float* __restrict__ bm3, float* __restrict__ out) {
    int wave = blockIdx.x * 4 + (threadIdx.x >> 6);
    int lane = threadIdx.x & 63;
    if (wave >= NB) return;
    const float* row = o2 + (size_t)wave * HD;
    float s = row[lane] * Wm3[lane] + row[lane + 64] * Wm3[lane + 64];
    for (int off = 32; off; off >>= 1) s += __shfl_down(s, off);
    if (lane == 0) out[wave] = s + bm3[0];
}

// ---------------- launcher ----------------
extern "C" void kernel_launch(void* const* d_in, const int* in_sizes, int n_in,
                              void* d_out, int out_size, void* d_ws, size_t ws_size,
                              hipStream_t stream)
{
    const float* sv_x   = (const float*)d_in[0];
    const int*   sv_ei  = (const int*)d_in[1];
    const float* su_x   = (const float*)d_in[3];
    const int*   su_ei  = (const int*)d_in[4];
    const float* ap     = (const float*)d_in[6];
    const float* bp     = (const float*)d_in[7];
    const float* sv_top = (const float*)d_in[8];
    const float* su_top = (const float*)d_in[9];
    const float* sv_hb  = (const float*)d_in[10];
    const float* su_hb  = (const float*)d_in[11];
    const float* T_x    = (const float*)d_in[12];
    const float* W_gcn1 = (const float*)d_in[13];
    const float* b_gcn1 = (const float*)d_in[14];
    const float* W_gcn2 = (const float*)d_in[15];
    const float* b_gcn2 = (const float*)d_in[16];
    const float* Wp     = (const float*)d_in[17];
    const float* bp_pr  = (const float*)d_in[18];
    const float* We1    = (const float*)d_in[19];
    const float* be1    = (const float*)d_in[20];
    const float* We2    = (const float*)d_in[21];
    const float* be2    = (const float*)d_in[22];
    const float* W_root = (const float*)d_in[23];
    const float* b_nn   = (const float*)d_in[24];
    const float* W_ih   = (const float*)d_in[25];
    const float* W_hh   = (const float*)d_in[26];
    const float* b_ih   = (const float*)d_in[27];
    const float* b_hh   = (const float*)d_in[28];
    const float* Wm1    = (const float*)d_in[29];
    const float* bm1    = (const float*)d_in[30];
    const float* Wm2    = (const float*)d_in[31];
    const float* bm2    = (const float*)d_in[32];
    const float* Wm3    = (const float*)d_in[33];
    const float* bm3    = (const float*)d_in[34];
    float* out = (float*)d_out;

    float* ws = (float*)d_ws;
    const size_t BIGF = (size_t)2 * NB * 4096;      // 33,554,432 floats
    // phase 1 (GCN): h_tmp, h_agg, A-split planes
    float* h_tmp = ws;                                         // NNODES*128
    float* h_agg = ws + 10485760;
    unsigned short* asph = (unsigned short*)(ws + 20971520);   // 81920x128 ushorts
    unsigned short* aspl = (unsigned short*)(ws + 26214400);
    // phase 2a (MPNN pre-Cbuf): node_feat planes [8192][160]
    unsigned short* ndfh = (unsigned short*)ws;                // 1,310,720 ushorts
    unsigned short* ndfl = (unsigned short*)(ws + 655360);
    // phase 2b: Cbuf
    float* Cbuf  = ws;
    // phase 3 (post-assembly): GRU/MLP temporaries
    float* gi    = ws;                        // 8192x384
    float* gh    = ws + 3145728;              // 8192x384
    float* o2    = ws + 6291456;              // 4096x128
    unsigned short* xgmh = (unsigned short*)(ws + 6815744);   // 4096x288
    unsigned short* xgml = (unsigned short*)(ws + 7405568);
    unsigned short* o1h  = (unsigned short*)(ws + 7995392);   // 4096x256
    unsigned short* o1l  = (unsigned short*)(ws + 8519680);   // ends 9,043,968 < BIGF
    // persistent small region
    float* p = ws + BIGF;
    float* xg    = p; p += (size_t)2 * NB * HD;
    float* h0    = p; p += (size_t)2 * NB * HD;
    float* tsv   = p; p += (size_t)NB * 32;
    float* tsu   = p; p += (size_t)NB * 32;
    float* vbuf  = p; p += (size_t)2 * NB * HD;
    float* aggrb = p; p += (size_t)2 * NB * HD;
    float* hout  = p; p += (size_t)2 * NB * HD;
    float* dinv  = p; p += NNODES;
    int* deg_i   = (int*)p; p += NNODES;
    int* row_ptr = (int*)p; p += NNODES;
    int* cursor  = (int*)p; p += NNODES;
    int* bsum    = (int*)p; p += 512;
    int* ssrc    = (int*)p; p += NEDGES;
    float* sw    = p; p += NEDGES;
    // split planes (sizes in floats = ushorts/2)
    unsigned short* h0sph = (unsigned short*)p; p += 524288;  // 8192x128
    unsigned short* h0spl = (unsigned short*)p; p += 524288;
    unsigned short* nfsph = (unsigned short*)p; p += 524288;
    unsigned short* nfspl = (unsigned short*)p; p += 524288;
    unsigned short* w1th  = (unsigned short*)p; p += 6144;    // 128x96
    unsigned short* w1tl  = (unsigned short*)p; p += 6144;
    unsigned short* w2th  = (unsigned short*)p; p += 8192;    // 128x128
    unsigned short* w2tl  = (unsigned short*)p; p += 8192;
    unsigned short* we2th = (unsigned short*)p; p += 262144;  // 4096x128
    unsigned short* we2tl = (unsigned short*)p; p += 262144;
    unsigned short* wihh  = (unsigned short*)p; p += 24576;   // 384x128
    unsigned short* wihl  = (unsigned short*)p; p += 24576;
    unsigned short* whhh  = (unsigned short*)p; p += 24576;
    unsigned short* whhl  = (unsigned short*)p; p += 24576;
    unsigned short* wpth  = (unsigned short*)p; p += 10240;   // 128x160
    unsigned short* wptl  = (unsigned short*)p; p += 10240;
    unsigned short* be2th = (unsigned short*)p; p += 8192;    // 128x128
    unsigned short* be2tl = (unsigned short*)p; p += 8192;
    unsigned short* wrth  = (unsigned short*)p; p += 8192;    // 128x128
    unsigned short* wrtl  = (unsigned short*)p; p += 8192;
    unsigned short* wm1th = (unsigned short*)p; p += 36864;   // 256x288
    unsigned short* wm1tl = (unsigned short*)p; p += 36864;
    unsigned short* wm2th = (unsigned short*)p; p += 16384;   // 128x256
    unsigned short* wm2tl = (unsigned short*)p; p += 16384;
    size_t need_bytes = (size_t)(p - ws) * sizeof(float);
    if (ws_size < need_bytes) {
        fill_kernel<<<(out_size + 255) / 256, 256, 0, stream>>>(out, -1.0e6f, out_size);
        return;
    }

    auto mgemm = [&](const unsigned short* Ah, const unsigned short* Al,
                     const unsigned short* Bh, const unsigned short* Bl,
                     const float* bias, const float* addend,
                     float* Cf, unsigned short* Chi, unsigned short* Clo,
                     int M, int Nn, int K, int ldc, int relu) {
        dim3 g(Nn / 128, M / 128);
        mfma_gemm_kernel<<<g, 256, 0, stream>>>(Ah, Al, Bh, Bl, bias, addend, Cf, Chi, Clo,
                                                M, Nn, K, ldc, relu);
    };

    // weight splits (recomputed every call; ws is re-poisoned each call)
    splitT_kernel<<<(128 * 96 + 255) / 256, 256, 0, stream>>>(W_gcn1, w1th, w1tl, 74, 128, 96);
    splitT_kernel<<<(128 * 128 + 255) / 256, 256, 0, stream>>>(W_gcn2, w2th, w2tl, 128, 128, 128);
    splitWe2_kernel<<<(4096 * 128 + 255) / 256, 256, 0, stream>>>(We2, we2th, we2tl);
    split_kernel<<<(384 * 128 + 255) / 256, 256, 0, stream>>>(W_ih, wihh, wihl, 384, 128, 128);
    split_kernel<<<(384 * 128 + 255) / 256, 256, 0, stream>>>(W_hh, whhh, whhl, 384, 128, 128);
    splitT_kernel<<<(128 * 160 + 255) / 256, 256, 0, stream>>>(Wp, wpth, wptl, 131, 128, 160);
    splitT_kernel<<<(128 * 128 + 255) / 256, 256, 0, stream>>>(be2, be2th, be2tl, 128, 128, 128);
    splitT_kernel<<<(128 * 128 + 255) / 256, 256, 0, stream>>>(W_root, wrth, wrtl, 128, 128, 128);
    splitT_kernel<<<(256 * 288 + 255) / 256, 256, 0, stream>>>(Wm1, wm1th, wm1tl, 257, 256, 288);
    splitT_kernel<<<(128 * 256 + 255) / 256, 256, 0, stream>>>(Wm2, wm2th, wm2tl, 256, 128, 256);

    auto run_gcn = [&](const float* x, const int* ei, float* xg_out) {
        const int* src = ei;
        const int* dst = ei + NEDGES;
        // CSR build
        fill_int_kernel<<<(NNODES + 255) / 256, 256, 0, stream>>>(deg_i, 0, NNODES);
        hist_kernel<<<(NEDGES + 255) / 256, 256, 0, stream>>>(dst, deg_i, NEDGES);
        dinv_kernel<<<(NNODES + 255) / 256, 256, 0, stream>>>(deg_i, dinv, NNODES);
        scan_block_kernel<<<NNODES / 256, 256, 0, stream>>>(deg_i, row_ptr, bsum);
        scan_bsum_kernel<<<1, 512, 0, stream>>>(bsum, NNODES / 256);
        add_offsets_kernel<<<NNODES / 256, 256, 0, stream>>>(row_ptr, bsum, cursor);
        csr_fill_kernel<<<(NEDGES + 255) / 256, 256, 0, stream>>>(src, dst, dinv, cursor, ssrc, sw, NEDGES);
        // conv1 (K=74 pad 96)
        split_kernel<<<(NNODES * 96 + 255) / 256, 256, 0, stream>>>(x, asph, aspl, NNODES, 74, 96);
        mgemm(asph, aspl, w1th, w1tl, nullptr, nullptr, h_tmp, nullptr, nullptr, NNODES, 128, 96, 128, 0);
        gather_kernel<<<(NNODES * 32 + 255) / 256, 256, 0, stream>>>(
            h_tmp, row_ptr, cursor, ssrc, sw, dinv, b_gcn1, nullptr, asph, aspl, 1);
        // conv2 (planes from gather)
        mgemm(asph, aspl, w2th, w2tl, nullptr, nullptr, h_tmp, nullptr, nullptr, NNODES, 128, 128, 128, 0);
        gather_kernel<<<(NNODES * 32 + 255) / 256, 256, 0, stream>>>(
            h_tmp, row_ptr, cursor, ssrc, sw, dinv, b_gcn2, h_agg, nullptr, nullptr, 0);
        pool_kernel<<<(NB * HD + 255) / 256, 256, 0, stream>>>(h_agg, xg_out);
    };

    run_gcn(sv_x, sv_ei, xg);
    run_gcn(su_x, su_ei, xg + (size_t)NB * HD);

    // MPNN
    node_feat_split_kernel<<<(2 * NB * 160 + 255) / 256, 256, 0, stream>>>(
        xg, ap, bp, sv_top, su_top, ndfh, ndfl);
    // h0 = relu(nodef @ Wp + bias): fp32 + planes
    mgemm(ndfh, ndfl, wpth, wptl, bp_pr, nullptr, h0, h0sph, h0spl, 2 * NB, 128, 160, 128, 1);
    edge_t_kernel<<<(NB * 32 + 255) / 256, 256, 0, stream>>>(sv_hb, su_hb, We1, be1, tsv, tsu);
    // vbuf = h0 @ reshape(be2)
    mgemm(h0sph, h0spl, be2th, be2tl, nullptr, nullptr, vbuf, nullptr, nullptr, 2 * NB, 128, 128, 128, 0);
    // Cbuf = h0 @ We2-view  (overwrites ndf planes - dead)
    mgemm(h0sph, h0spl, we2th, we2tl, nullptr, nullptr, Cbuf, nullptr, nullptr, 2 * NB, 4096, 128, 4096, 0);
    assembly_kernel<<<NB, 128, 0, stream>>>(Cbuf, vbuf, tsv, tsu, aggrb);
    // nf = relu(h0 @ W_root + aggr + b_nn) -> planes only
    mgemm(h0sph, h0spl, wrth, wrtl, b_nn, aggrb, nullptr, nfsph, nfspl, 2 * NB, 128, 128, 128, 1);
    // GRU gates (Cbuf dead -> gi/gh region)
    mgemm(nfsph, nfspl, wihh, wihl, b_ih, nullptr, gi, nullptr, nullptr, 2 * NB, 384, 128, 384, 0);
    mgemm(h0sph, h0spl, whhh, whhl, b_hh, nullptr, gh, nullptr, nullptr, 2 * NB, 384, 128, 384, 0);
    gru_kernel<<<(2 * NB * HD + 255) / 256, 256, 0, stream>>>(gi, gh, h0, hout);
    // output MLP (all MFMA; o1 planes only)
    xgm_split_kernel<<<(NB * 288 + 255) / 256, 256, 0, stream>>>(hout, T_x, xgmh, xgml);
    mgemm(xgmh, xgml, wm1th, wm1tl, bm1, nullptr, nullptr, o1h, o1l, NB, 256, 288, 256, 1);
    mgemm(o1h, o1l, wm2th, wm2tl, bm2, nullptr, o2, nullptr, nullptr, NB, 128, 256, 128, 1);
    matvec_kernel<<<NB / 4, 256, 0, stream>>>(o2, Wm3, bm3, out);
}